// Round 1
// baseline (1163.090 us; speedup 1.0000x reference)
//
#include <hip/hip_runtime.h>

// BClassifier fused pipeline for MI355X (gfx950).
// ws layout (bytes), total ~130 MB:
//   H      @ 0          : 131072x512 bf16 = 134217728
//   a/A    @ 134217728  : 131072 f32      = 524288
//   W1T    @ 134742016  : 512x1024 bf16   = 1048576
//   WaT    @ 135790592  : 128x512 bf16    = 131072
//   bag    @ 135921664  : 32x512 f32      = 65536
//   cm     @ 135987200  : 2x512 f32       = 4096
//   cmn    @ 135991296  : 2 f32 (pad 256)
//   dists  @ 135991552  : 2x256 f32       = 2048

#define EPSF 1e-8f

typedef float v4f __attribute__((ext_vector_type(4)));
typedef short v8s __attribute__((ext_vector_type(8)));

__device__ __forceinline__ unsigned short f2bf(float f) {
  unsigned u = __float_as_uint(f);
  u = (u + 0x7fffu + ((u >> 16) & 1u)) >> 16;  // RNE
  return (unsigned short)u;
}
__device__ __forceinline__ float bf2f(unsigned short b) {
  return __uint_as_float(((unsigned)b) << 16);
}
__device__ __forceinline__ void gll16(const void* g, void* l) {
  __builtin_amdgcn_global_load_lds((const __attribute__((address_space(1))) void*)g,
                                   (__attribute__((address_space(3))) void*)l, 16, 0, 0);
}

// ---- prep: W1 [1024][500] f32 -> W1T [512][1024] bf16 (zero-padded cols) ----
__global__ void k0_w1t(const float* __restrict__ W1, unsigned short* __restrict__ W1T) {
  int idx = blockIdx.x * 256 + threadIdx.x;  // 512*1024
  int n = idx >> 10, k = idx & 1023;
  float v = (n < 500) ? W1[k * 500 + n] : 0.f;
  W1T[idx] = f2bf(v);
}
// ---- prep: Wa [500][128] f32 -> WaT [128][512] bf16 (zero-padded rows) ----
__global__ void k0_wat(const float* __restrict__ Wa, unsigned short* __restrict__ WaT) {
  int idx = blockIdx.x * 256 + threadIdx.x;  // 128*512
  int d = idx >> 9, l = idx & 511;
  float v = (l < 500) ? Wa[l * 128 + d] : 0.f;
  WaT[idx] = f2bf(v);
}

// ---- GEMM1: H = relu(x @ W1 + b1), bf16 out [131072][512] (cols>=500 are 0) ----
__global__ __launch_bounds__(256) void k1_gemm1(const float* __restrict__ x,
    const unsigned short* __restrict__ W1T, const float* __restrict__ b1,
    unsigned short* __restrict__ H) {
  __shared__ float As[128 * 64];            // A tile fp32 (cvt to bf16 on read)
  __shared__ unsigned short Bs[128 * 64];   // B tile bf16, [n][k]
  int bid = blockIdx.x;
  int n0 = (bid & 3) * 128;                 // n fastest: 4 blocks share A tile (L2/L3)
  size_t m0 = (size_t)(bid >> 2) * 128;
  int tid = threadIdx.x;
  int lane = tid & 63, wv = tid >> 6;
  int wm = (wv >> 1) * 64, wn = (wv & 1) * 64;
  int l15 = lane & 15, quad = lane >> 4;
  v4f acc[4][4];
  for (int i = 0; i < 4; i++)
    for (int j = 0; j < 4; j++) acc[i][j] = (v4f)(0.f);

  for (int kt = 0; kt < 1024; kt += 64) {
    const float* gA = x + m0 * 1024 + kt;
    const unsigned short* gB = W1T + (size_t)n0 * 1024 + kt;
#pragma unroll
    for (int p = 0; p < 8; p++) {  // 128 rows x 16 chunks of 4 floats
      int ci = p * 256 + tid;
      gll16(gA + (size_t)(ci >> 4) * 1024 + (ci & 15) * 4, As + ci * 4);
    }
#pragma unroll
    for (int p = 0; p < 4; p++) {  // 128 rows x 8 chunks of 8 bf16
      int ci = p * 256 + tid;
      gll16(gB + (size_t)(ci >> 3) * 1024 + (ci & 7) * 8, Bs + ci * 8);
    }
    __syncthreads();
#pragma unroll
    for (int kk = 0; kk < 64; kk += 32) {
      v8s af[4], bf[4];
#pragma unroll
      for (int mi = 0; mi < 4; mi++) {
        const float* p = As + (wm + mi * 16 + l15) * 64 + kk + quad * 8;
        v4f lo = *(const v4f*)p;
        v4f hi = *(const v4f*)(p + 4);
        v8s t;
        t[0] = (short)f2bf(lo.x); t[1] = (short)f2bf(lo.y);
        t[2] = (short)f2bf(lo.z); t[3] = (short)f2bf(lo.w);
        t[4] = (short)f2bf(hi.x); t[5] = (short)f2bf(hi.y);
        t[6] = (short)f2bf(hi.z); t[7] = (short)f2bf(hi.w);
        af[mi] = t;
      }
#pragma unroll
      for (int ni = 0; ni < 4; ni++)
        bf[ni] = *(const v8s*)(Bs + (wn + ni * 16 + l15) * 64 + kk + quad * 8);
#pragma unroll
      for (int mi = 0; mi < 4; mi++)
#pragma unroll
        for (int ni = 0; ni < 4; ni++)
          acc[mi][ni] = __builtin_amdgcn_mfma_f32_16x16x32_bf16(af[mi], bf[ni], acc[mi][ni], 0, 0, 0);
    }
    __syncthreads();
  }
#pragma unroll
  for (int mi = 0; mi < 4; mi++) {
#pragma unroll
    for (int ni = 0; ni < 4; ni++) {
      int col = n0 + wn + ni * 16 + l15;
      float bias = (col < 500) ? b1[col] : 0.f;
#pragma unroll
      for (int r = 0; r < 4; r++) {
        size_t row = m0 + wm + mi * 16 + quad * 4 + r;
        float v = (col < 500) ? fmaxf(acc[mi][ni][r] + bias, 0.f) : 0.f;
        H[row * 512 + col] = f2bf(v);
      }
    }
  }
}

// ---- GEMM2: a = relu(H @ Wa + ba) @ Va + bv  -> [131072] f32 ----
__global__ __launch_bounds__(256) void k2_attn(const unsigned short* __restrict__ H,
    const unsigned short* __restrict__ WaT, const float* __restrict__ ba,
    const float* __restrict__ Va, const float* __restrict__ bv,
    float* __restrict__ aout) {
  __shared__ unsigned short Hs[128 * 64];
  __shared__ unsigned short Ws[128 * 64];
  size_t m0 = (size_t)blockIdx.x * 128;
  int tid = threadIdx.x;
  int lane = tid & 63, wv = tid >> 6;
  int wm = wv * 32;  // each wave owns 32 rows, all 128 cols
  int l15 = lane & 15, quad = lane >> 4;
  v4f acc[2][8];
  for (int i = 0; i < 2; i++)
    for (int j = 0; j < 8; j++) acc[i][j] = (v4f)(0.f);

  for (int kt = 0; kt < 512; kt += 64) {
    const unsigned short* gH = H + m0 * 512 + kt;
    const unsigned short* gW = WaT + kt;
#pragma unroll
    for (int p = 0; p < 4; p++) {
      int ci = p * 256 + tid;
      gll16(gH + (size_t)(ci >> 3) * 512 + (ci & 7) * 8, Hs + ci * 8);
    }
#pragma unroll
    for (int p = 0; p < 4; p++) {
      int ci = p * 256 + tid;
      gll16(gW + (size_t)(ci >> 3) * 512 + (ci & 7) * 8, Ws + ci * 8);
    }
    __syncthreads();
#pragma unroll
    for (int kk = 0; kk < 64; kk += 32) {
      v8s af[2], bf[8];
#pragma unroll
      for (int mi = 0; mi < 2; mi++)
        af[mi] = *(const v8s*)(Hs + (wm + mi * 16 + l15) * 64 + kk + quad * 8);
#pragma unroll
      for (int ni = 0; ni < 8; ni++)
        bf[ni] = *(const v8s*)(Ws + (ni * 16 + l15) * 64 + kk + quad * 8);
#pragma unroll
      for (int mi = 0; mi < 2; mi++)
#pragma unroll
        for (int ni = 0; ni < 8; ni++)
          acc[mi][ni] = __builtin_amdgcn_mfma_f32_16x16x32_bf16(af[mi], bf[ni], acc[mi][ni], 0, 0, 0);
    }
    __syncthreads();
  }
  float bav[8], vav[8];
#pragma unroll
  for (int ni = 0; ni < 8; ni++) {
    int n = ni * 16 + l15;
    bav[ni] = ba[n];
    vav[ni] = Va[n];
  }
  float bv0 = bv[0];
#pragma unroll
  for (int mi = 0; mi < 2; mi++) {
#pragma unroll
    for (int r = 0; r < 4; r++) {
      float s = 0.f;
#pragma unroll
      for (int ni = 0; ni < 8; ni++) s += fmaxf(acc[mi][ni][r] + bav[ni], 0.f) * vav[ni];
      s += __shfl_xor(s, 1); s += __shfl_xor(s, 2);
      s += __shfl_xor(s, 4); s += __shfl_xor(s, 8);
      if (l15 == 0) aout[m0 + wm + mi * 16 + quad * 4 + r] = s + bv0;
    }
  }
}

// ---- softmax over N=4096 per bag, in place ----
__global__ void k3_softmax(float* __restrict__ a) {
  __shared__ float red[256];
  int b = blockIdx.x, tid = threadIdx.x;
  float* row = a + b * 4096;
  float m = -1e30f;
  for (int i = tid; i < 4096; i += 256) m = fmaxf(m, row[i]);
  red[tid] = m; __syncthreads();
  for (int s = 128; s > 0; s >>= 1) { if (tid < s) red[tid] = fmaxf(red[tid], red[tid + s]); __syncthreads(); }
  m = red[0]; __syncthreads();
  float sum = 0.f;
  for (int i = tid; i < 4096; i += 256) { float e = expf(row[i] - m); row[i] = e; sum += e; }
  red[tid] = sum; __syncthreads();
  for (int s = 128; s > 0; s >>= 1) { if (tid < s) red[tid] += red[tid + s]; __syncthreads(); }
  float inv = 1.f / red[0];
  for (int i = tid; i < 4096; i += 256) row[i] *= inv;
}

// ---- bag_feat[b][l] = sum_n A[b][n] * H[b,n,l], atomic accumulate ----
__global__ void k4_bag(const unsigned short* __restrict__ H, const float* __restrict__ A,
                       float* __restrict__ bag) {
  int bid = blockIdx.x;          // 32 bags x 16 chunks
  int b = bid >> 4, ch = bid & 15;
  int tid = threadIdx.x;
  size_t base = ((size_t)b * 4096 + ch * 256) * 512;
  const float* Ab = A + b * 4096 + ch * 256;
  float s0 = 0.f, s1 = 0.f;
  for (int n = 0; n < 256; n += 4) {
#pragma unroll
    for (int j = 0; j < 4; j++) {
      float w = Ab[n + j];
      unsigned hv = *(const unsigned*)(H + base + (size_t)(n + j) * 512 + tid * 2);
      s0 += w * bf2f((unsigned short)(hv & 0xffffu));
      s1 += w * bf2f((unsigned short)(hv >> 16));
    }
  }
  atomicAdd(&bag[b * 512 + tid * 2], s0);
  atomicAdd(&bag[b * 512 + tid * 2 + 1], s1);
}

// ---- copy rehearsal -> out[66..] ----
__global__ void k5_copy(const float* __restrict__ reh, float* __restrict__ out) {
  int idx = blockIdx.x * 256 + threadIdx.x;
  if (idx < 256000) out[66 + idx] = reh[idx];
}

// ---- cls_means [2][512] (pad 0) ----
__global__ void k5_means(const float* __restrict__ reh, float* __restrict__ cm) {
  int idx = blockIdx.x * 256 + threadIdx.x;  // 1024
  int c = idx >> 9, l = idx & 511;
  float s = 0.f;
  if (l < 500) {
    const float* p = reh + c * 128000 + l;
    for (int q = 0; q < 256; q++) s += p[q * 500];
    s *= (1.f / 256.f);
  }
  cm[idx] = s;
}

__global__ void k5_cmnorm(const float* __restrict__ cm, float* __restrict__ cmn) {
  __shared__ float red[256];
  int c = blockIdx.x, tid = threadIdx.x;
  float v = 0.f;
  for (int l = tid; l < 512; l += 256) { float x = cm[c * 512 + l]; v += x * x; }
  red[tid] = v; __syncthreads();
  for (int s = 128; s > 0; s >>= 1) { if (tid < s) red[tid] += red[tid + s]; __syncthreads(); }
  if (tid == 0) cmn[c] = sqrtf(red[0]);
}

// ---- cls_dists[c][p] = cos(cls_means[c], reh[c][p]) with torch-eps semantics ----
__global__ void k5_dists(const float* __restrict__ reh, const float* __restrict__ cm,
                         const float* __restrict__ cmn, float* __restrict__ dists) {
  int bid = blockIdx.x;  // 512
  int c = bid >> 8, p = bid & 255;
  int lane = threadIdx.x;  // 64
  const float* row = reh + (c * 256 + p) * 500;
  const float* cmr = cm + c * 512;
  float dot = 0.f, n2 = 0.f;
  for (int l = lane; l < 500; l += 64) { float r = row[l]; dot += r * cmr[l]; n2 += r * r; }
#pragma unroll
  for (int m = 32; m > 0; m >>= 1) { dot += __shfl_xor(dot, m); n2 += __shfl_xor(n2, m); }
  if (lane == 0)
    dists[c * 256 + p] = dot / (fmaxf(cmn[c], EPSF) * fmaxf(sqrtf(n2), EPSF));
}

// ---- head: logits_mlp, loss, reg, sequential rehearsal scan + row writes ----
__global__ __launch_bounds__(256) void k5_head(const float* __restrict__ bag,
    const float* __restrict__ cm, const float* __restrict__ cmn,
    const float* __restrict__ distsIn, const int* __restrict__ y,
    const float* __restrict__ Wc, const float* __restrict__ bc,
    float* __restrict__ out) {
  __shared__ float simL[32][2], logitL[32][2], bagn[32];
  __shared__ float dists[512];
  __shared__ int owner[512];
  __shared__ float rv[256];
  __shared__ int ri[256];
  __shared__ float dot01S;
  int tid = threadIdx.x;
  int lane = tid & 63, wv = tid >> 6;
  // phase 1: per-bag raw dots with cls_means, Wc, and norms
  for (int j = 0; j < 8; j++) {
    int b = wv * 8 + j;
    const float* br = bag + b * 512;
    float s0 = 0, s1 = 0, w0 = 0, w1 = 0, n2 = 0;
    for (int l = lane; l < 500; l += 64) {
      float v = br[l];
      s0 += v * cm[l]; s1 += v * cm[512 + l];
      w0 += v * Wc[l * 2]; w1 += v * Wc[l * 2 + 1];
      n2 += v * v;
    }
#pragma unroll
    for (int m = 32; m > 0; m >>= 1) {
      s0 += __shfl_xor(s0, m); s1 += __shfl_xor(s1, m);
      w0 += __shfl_xor(w0, m); w1 += __shfl_xor(w1, m);
      n2 += __shfl_xor(n2, m);
    }
    if (lane == 0) {
      simL[b][0] = s0; simL[b][1] = s1;
      logitL[b][0] = w0 + bc[0]; logitL[b][1] = w1 + bc[1];
      bagn[b] = sqrtf(n2);
    }
  }
  if (wv == 0) {
    float d = 0.f;
    for (int l = lane; l < 500; l += 64) d += cm[l] * cm[512 + l];
#pragma unroll
    for (int m = 32; m > 0; m >>= 1) d += __shfl_xor(d, m);
    if (lane == 0) dot01S = d;
  }
  dists[tid] = distsIn[tid]; dists[tid + 256] = distsIn[tid + 256];
  owner[tid] = -1; owner[tid + 256] = -1;
  __syncthreads();
  // outputs
  if (tid < 64) out[tid] = logitL[tid >> 1][tid & 1];
  if (tid == 0) {
    float acc = 0.f;
    for (int b = 0; b < 32; b++) {
      int yb = y[b];
      float p = simL[b][yb] * 2.0f;        // /TEMP, TEMP=0.5
      float ng = simL[b][1 - yb] * 2.0f;
      float mx = fmaxf(p, ng);
      float lse = mx + logf(expf(p - mx) + expf(ng - mx));
      acc += p - lse;
    }
    out[64] = -acc / 32.f;
    out[65] = 1.f + dot01S / (fmaxf(cmn[0], EPSF) * fmaxf(cmn[1], EPSF));
  }
  __syncthreads();
  // sequential scan, 32 steps; argmin with first-index tie-break
  for (int i = 0; i < 32; i++) {
    int ci = y[i];
    rv[tid] = dists[ci * 256 + tid]; ri[tid] = tid;
    __syncthreads();
    for (int s = 128; s > 0; s >>= 1) {
      if (tid < s) {
        float ov = rv[tid + s]; int oi = ri[tid + s];
        if (ov < rv[tid] || (ov == rv[tid] && oi < ri[tid])) { rv[tid] = ov; ri[tid] = oi; }
      }
      __syncthreads();
    }
    if (tid == 0) {
      float mv = rv[0]; int idx = ri[0];
      float d = simL[i][ci] / (fmaxf(cmn[ci], EPSF) * fmaxf(bagn[i], EPSF));
      if (d > mv) { dists[ci * 256 + idx] = d; owner[ci * 256 + idx] = i; }
    }
    __syncthreads();
  }
  // write replaced rows (last writer per slot wins; owner holds it)
  for (int s = 0; s < 512; s++) {
    int o = owner[s];
    if (o >= 0)
      for (int l = tid; l < 500; l += 256) out[66 + s * 500 + l] = bag[o * 512 + l];
  }
}

extern "C" void kernel_launch(void* const* d_in, const int* in_sizes, int n_in,
                              void* d_out, int out_size, void* d_ws, size_t ws_size,
                              hipStream_t stream) {
  const float* x  = (const float*)d_in[0];
  const int*   y  = (const int*)d_in[1];
  const float* W1 = (const float*)d_in[2];
  const float* b1 = (const float*)d_in[3];
  const float* Wa = (const float*)d_in[4];
  const float* ba = (const float*)d_in[5];
  const float* Va = (const float*)d_in[6];
  const float* bv = (const float*)d_in[7];
  const float* Wc = (const float*)d_in[8];
  const float* bc = (const float*)d_in[9];
  const float* reh = (const float*)d_in[10];
  float* out = (float*)d_out;

  char* ws = (char*)d_ws;
  unsigned short* H   = (unsigned short*)ws;
  float*          a   = (float*)(ws + 134217728);
  unsigned short* W1T = (unsigned short*)(ws + 134742016);
  unsigned short* WaT = (unsigned short*)(ws + 135790592);
  float*          bag = (float*)(ws + 135921664);
  float*          cm  = (float*)(ws + 135987200);
  float*          cmn = (float*)(ws + 135991296);
  float*          dst = (float*)(ws + 135991552);

  hipMemsetAsync(bag, 0, 65536, stream);
  k0_w1t<<<2048, 256, 0, stream>>>(W1, W1T);
  k0_wat<<<256, 256, 0, stream>>>(Wa, WaT);
  k1_gemm1<<<4096, 256, 0, stream>>>(x, W1T, b1, H);
  k2_attn<<<1024, 256, 0, stream>>>(H, WaT, ba, Va, bv, a);
  k3_softmax<<<32, 256, 0, stream>>>(a);
  k4_bag<<<512, 256, 0, stream>>>(H, a, bag);
  k5_copy<<<1001, 256, 0, stream>>>(reh, out);
  k5_means<<<4, 256, 0, stream>>>(reh, cm);
  k5_cmnorm<<<2, 256, 0, stream>>>(cm, cmn);
  k5_dists<<<512, 64, 0, stream>>>(reh, cm, cmn, dst);
  k5_head<<<1, 256, 0, stream>>>(bag, cm, cmn, dst, y, Wc, bc, out);
}

// Round 2
// 1080.143 us; speedup vs baseline: 1.0768x; 1.0768x over previous
//
#include <hip/hip_runtime.h>

// BClassifier fused pipeline for MI355X (gfx950). Round 2:
//  - XOR-swizzled LDS tiles (swizzle applied on the GLOBAL side of
//    global_load_lds, since its LDS side is fixed to base+lane*16)
//  - XCD-aware block remap in GEMM1 (4 n-tiles of one m-tile on same XCD)
//  - v_perm truncate-pack f32->bf16 (1 VALU per 2 elements)
//  - k5_means coalesced; k5_head scan in registers (wave 0, no barriers)

#define EPSF 1e-8f

typedef float v4f __attribute__((ext_vector_type(4)));
typedef short v8s __attribute__((ext_vector_type(8)));

__device__ __forceinline__ unsigned short f2bf(float f) {
  unsigned u = __float_as_uint(f);
  u = (u + 0x7fffu + ((u >> 16) & 1u)) >> 16;  // RNE
  return (unsigned short)u;
}
__device__ __forceinline__ float bf2f(unsigned short b) {
  return __uint_as_float(((unsigned)b) << 16);
}
// pack two floats' high halves: low short = trunc(a), high short = trunc(b)
__device__ __forceinline__ unsigned pk(float a, float b) {
  return __builtin_amdgcn_perm(__float_as_uint(b), __float_as_uint(a), 0x07060302u);
}
__device__ __forceinline__ void gll16(const void* g, void* l) {
  __builtin_amdgcn_global_load_lds((const __attribute__((address_space(1))) void*)g,
                                   (__attribute__((address_space(3))) void*)l, 16, 0, 0);
}

// ---- prep: W1 [1024][500] f32 -> W1T [512][1024] bf16 (zero-padded cols) ----
__global__ void k0_w1t(const float* __restrict__ W1, unsigned short* __restrict__ W1T) {
  int idx = blockIdx.x * 256 + threadIdx.x;  // 512*1024
  int n = idx >> 10, k = idx & 1023;
  float v = (n < 500) ? W1[k * 500 + n] : 0.f;
  W1T[idx] = f2bf(v);
}
// ---- prep: Wa [500][128] f32 -> WaT [128][512] bf16 (zero-padded rows) ----
__global__ void k0_wat(const float* __restrict__ Wa, unsigned short* __restrict__ WaT) {
  int idx = blockIdx.x * 256 + threadIdx.x;  // 128*512
  int d = idx >> 9, l = idx & 511;
  float v = (l < 500) ? Wa[l * 128 + d] : 0.f;
  WaT[idx] = f2bf(v);
}

// ---- GEMM1: H = relu(x @ W1 + b1), bf16 out [131072][512] (cols>=500 are 0) ----
__global__ __launch_bounds__(256) void k1_gemm1(const float* __restrict__ x,
    const unsigned short* __restrict__ W1T, const float* __restrict__ b1,
    unsigned short* __restrict__ H) {
  __shared__ float As[128 * 64];            // fp32 A tile, 16B-chunk xor-swizzled
  __shared__ unsigned short Bs[128 * 64];   // bf16 B tile [n][k], swizzled
  int bid = blockIdx.x;
  // XCD grouping: xcd = bid&7 owns m-tiles [xcd*128, xcd*128+128); n fastest
  int x8 = bid & 7, j = bid >> 3;
  int mb = x8 * 128 + (j >> 2);
  int n0 = (j & 3) * 128;
  size_t m0 = (size_t)mb * 128;
  int tid = threadIdx.x;
  int lane = tid & 63, wv = tid >> 6;
  int wm = (wv >> 1) * 64, wn = (wv & 1) * 64;
  int l15 = lane & 15, quad = lane >> 4, m7 = l15 & 7;
  v4f acc[4][4];
  for (int i = 0; i < 4; i++)
    for (int jj = 0; jj < 4; jj++) acc[i][jj] = (v4f)(0.f);

  for (int kt = 0; kt < 1024; kt += 64) {
    const float* gA = x + m0 * 1024 + kt;
    const unsigned short* gB = W1T + (size_t)n0 * 1024 + kt;
#pragma unroll
    for (int p = 0; p < 8; p++) {  // A: 128 rows x 16 chunks of 16B
      int ci = p * 256 + tid;
      int r = ci >> 4, pc = ci & 15;
      int c = pc ^ (r & 7);
      gll16(gA + (size_t)r * 1024 + c * 4, As + ci * 4);
    }
#pragma unroll
    for (int p = 0; p < 4; p++) {  // B: 128 rows x 8 chunks of 16B
      int ci = p * 256 + tid;
      int r = ci >> 3, pc = ci & 7;
      int c = pc ^ (r & 7);
      gll16(gB + (size_t)r * 1024 + c * 8, Bs + ci * 8);
    }
    __syncthreads();
#pragma unroll
    for (int kk = 0; kk < 64; kk += 32) {
      v8s af[4], bf[4];
      int c0 = (kk >> 2) + 2 * quad;   // fp32 chunk (even)
      int cb = (kk >> 3) + quad;       // bf16 chunk
#pragma unroll
      for (int mi = 0; mi < 4; mi++) {
        const float* rowp = As + (wm + mi * 16 + l15) * 64;
        v4f lo = *(const v4f*)(rowp + ((c0 ^ m7) << 2));
        v4f hi = *(const v4f*)(rowp + (((c0 + 1) ^ m7) << 2));
        union { unsigned u[4]; v8s v; } t;
        t.u[0] = pk(lo.x, lo.y); t.u[1] = pk(lo.z, lo.w);
        t.u[2] = pk(hi.x, hi.y); t.u[3] = pk(hi.z, hi.w);
        af[mi] = t.v;
      }
#pragma unroll
      for (int ni = 0; ni < 4; ni++)
        bf[ni] = *(const v8s*)(Bs + (wn + ni * 16 + l15) * 64 + ((cb ^ m7) << 3));
#pragma unroll
      for (int mi = 0; mi < 4; mi++)
#pragma unroll
        for (int ni = 0; ni < 4; ni++)
          acc[mi][ni] = __builtin_amdgcn_mfma_f32_16x16x32_bf16(af[mi], bf[ni], acc[mi][ni], 0, 0, 0);
    }
    __syncthreads();
  }
#pragma unroll
  for (int mi = 0; mi < 4; mi++) {
#pragma unroll
    for (int ni = 0; ni < 4; ni++) {
      int col = n0 + wn + ni * 16 + l15;
      float bias = (col < 500) ? b1[col] : 0.f;
#pragma unroll
      for (int r = 0; r < 4; r++) {
        size_t row = m0 + wm + mi * 16 + quad * 4 + r;
        float v = (col < 500) ? fmaxf(acc[mi][ni][r] + bias, 0.f) : 0.f;
        H[row * 512 + col] = f2bf(v);
      }
    }
  }
}

// ---- GEMM2: a = relu(H @ Wa + ba) @ Va + bv  -> [131072] f32 ----
__global__ __launch_bounds__(256) void k2_attn(const unsigned short* __restrict__ H,
    const unsigned short* __restrict__ WaT, const float* __restrict__ ba,
    const float* __restrict__ Va, const float* __restrict__ bv,
    float* __restrict__ aout) {
  __shared__ unsigned short Hs[128 * 64];
  __shared__ unsigned short Ws[128 * 64];
  size_t m0 = (size_t)blockIdx.x * 128;
  int tid = threadIdx.x;
  int lane = tid & 63, wv = tid >> 6;
  int wm = wv * 32;  // each wave owns 32 rows, all 128 cols
  int l15 = lane & 15, quad = lane >> 4, m7 = l15 & 7;
  v4f acc[2][8];
  for (int i = 0; i < 2; i++)
    for (int jj = 0; jj < 8; jj++) acc[i][jj] = (v4f)(0.f);

  for (int kt = 0; kt < 512; kt += 64) {
    const unsigned short* gH = H + m0 * 512 + kt;
    const unsigned short* gW = WaT + kt;
#pragma unroll
    for (int p = 0; p < 4; p++) {
      int ci = p * 256 + tid;
      int r = ci >> 3, pc = ci & 7;
      int c = pc ^ (r & 7);
      gll16(gH + (size_t)r * 512 + c * 8, Hs + ci * 8);
    }
#pragma unroll
    for (int p = 0; p < 4; p++) {
      int ci = p * 256 + tid;
      int r = ci >> 3, pc = ci & 7;
      int c = pc ^ (r & 7);
      gll16(gW + (size_t)r * 512 + c * 8, Ws + ci * 8);
    }
    __syncthreads();
#pragma unroll
    for (int kk = 0; kk < 64; kk += 32) {
      v8s af[2], bf[8];
      int cb = (kk >> 3) + quad;
#pragma unroll
      for (int mi = 0; mi < 2; mi++)
        af[mi] = *(const v8s*)(Hs + (wm + mi * 16 + l15) * 64 + ((cb ^ m7) << 3));
#pragma unroll
      for (int ni = 0; ni < 8; ni++)
        bf[ni] = *(const v8s*)(Ws + (ni * 16 + l15) * 64 + ((cb ^ m7) << 3));
#pragma unroll
      for (int mi = 0; mi < 2; mi++)
#pragma unroll
        for (int ni = 0; ni < 8; ni++)
          acc[mi][ni] = __builtin_amdgcn_mfma_f32_16x16x32_bf16(af[mi], bf[ni], acc[mi][ni], 0, 0, 0);
    }
    __syncthreads();
  }
  float bav[8], vav[8];
#pragma unroll
  for (int ni = 0; ni < 8; ni++) {
    int n = ni * 16 + l15;
    bav[ni] = ba[n];
    vav[ni] = Va[n];
  }
  float bv0 = bv[0];
#pragma unroll
  for (int mi = 0; mi < 2; mi++) {
#pragma unroll
    for (int r = 0; r < 4; r++) {
      float s = 0.f;
#pragma unroll
      for (int ni = 0; ni < 8; ni++) s += fmaxf(acc[mi][ni][r] + bav[ni], 0.f) * vav[ni];
      s += __shfl_xor(s, 1); s += __shfl_xor(s, 2);
      s += __shfl_xor(s, 4); s += __shfl_xor(s, 8);
      if (l15 == 0) aout[m0 + wm + mi * 16 + quad * 4 + r] = s + bv0;
    }
  }
}

// ---- softmax over N=4096 per bag, in place ----
__global__ void k3_softmax(float* __restrict__ a) {
  __shared__ float red[256];
  int b = blockIdx.x, tid = threadIdx.x;
  float* row = a + b * 4096;
  float m = -1e30f;
  for (int i = tid; i < 4096; i += 256) m = fmaxf(m, row[i]);
  red[tid] = m; __syncthreads();
  for (int s = 128; s > 0; s >>= 1) { if (tid < s) red[tid] = fmaxf(red[tid], red[tid + s]); __syncthreads(); }
  m = red[0]; __syncthreads();
  float sum = 0.f;
  for (int i = tid; i < 4096; i += 256) { float e = expf(row[i] - m); row[i] = e; sum += e; }
  red[tid] = sum; __syncthreads();
  for (int s = 128; s > 0; s >>= 1) { if (tid < s) red[tid] += red[tid + s]; __syncthreads(); }
  float inv = 1.f / red[0];
  for (int i = tid; i < 4096; i += 256) row[i] *= inv;
}

// ---- bag_feat[b][l] = sum_n A[b][n] * H[b,n,l], atomic accumulate ----
__global__ void k4_bag(const unsigned short* __restrict__ H, const float* __restrict__ A,
                       float* __restrict__ bag) {
  int bid = blockIdx.x;          // 32 bags x 16 chunks
  int b = bid >> 4, ch = bid & 15;
  int tid = threadIdx.x;
  size_t base = ((size_t)b * 4096 + ch * 256) * 512;
  const float* Ab = A + b * 4096 + ch * 256;
  float s0 = 0.f, s1 = 0.f;
  for (int n = 0; n < 256; n += 4) {
#pragma unroll
    for (int jj = 0; jj < 4; jj++) {
      float w = Ab[n + jj];
      unsigned hv = *(const unsigned*)(H + base + (size_t)(n + jj) * 512 + tid * 2);
      s0 += w * bf2f((unsigned short)(hv & 0xffffu));
      s1 += w * bf2f((unsigned short)(hv >> 16));
    }
  }
  atomicAdd(&bag[b * 512 + tid * 2], s0);
  atomicAdd(&bag[b * 512 + tid * 2 + 1], s1);
}

// ---- copy rehearsal -> out[66..] ----
__global__ void k5_copy(const float* __restrict__ reh, float* __restrict__ out) {
  int idx = blockIdx.x * 256 + threadIdx.x;
  if (idx < 256000) out[66 + idx] = reh[idx];
}

// ---- cls_means [2][512] (pad 0), coalesced row accumulation ----
__global__ void k5_means(const float* __restrict__ reh, float* __restrict__ cm) {
  int c = blockIdx.x, tid = threadIdx.x;  // grid 2 x 256
  const float* base = reh + c * 128000;
  float s0 = 0.f, s1 = 0.f;
  for (int q = 0; q < 256; q++) {
    const float* row = base + q * 500;
    s0 += row[tid];
    if (tid + 256 < 500) s1 += row[tid + 256];
  }
  cm[c * 512 + tid] = s0 * (1.f / 256.f);
  int l2 = tid + 256;
  cm[c * 512 + l2] = (l2 < 500) ? s1 * (1.f / 256.f) : 0.f;
}

__global__ void k5_cmnorm(const float* __restrict__ cm, float* __restrict__ cmn) {
  __shared__ float red[256];
  int c = blockIdx.x, tid = threadIdx.x;
  float v = 0.f;
  for (int l = tid; l < 512; l += 256) { float xx = cm[c * 512 + l]; v += xx * xx; }
  red[tid] = v; __syncthreads();
  for (int s = 128; s > 0; s >>= 1) { if (tid < s) red[tid] += red[tid + s]; __syncthreads(); }
  if (tid == 0) cmn[c] = sqrtf(red[0]);
}

// ---- cls_dists[c][p] = cos(cls_means[c], reh[c][p]) ----
__global__ void k5_dists(const float* __restrict__ reh, const float* __restrict__ cm,
                         const float* __restrict__ cmn, float* __restrict__ dists) {
  int bid = blockIdx.x;  // 512
  int c = bid >> 8, p = bid & 255;
  int lane = threadIdx.x;  // 64
  const float* row = reh + (c * 256 + p) * 500;
  const float* cmr = cm + c * 512;
  float dot = 0.f, n2 = 0.f;
  for (int l = lane; l < 500; l += 64) { float r = row[l]; dot += r * cmr[l]; n2 += r * r; }
#pragma unroll
  for (int m = 32; m > 0; m >>= 1) { dot += __shfl_xor(dot, m); n2 += __shfl_xor(n2, m); }
  if (lane == 0)
    dists[c * 256 + p] = dot / (fmaxf(cmn[c], EPSF) * fmaxf(sqrtf(n2), EPSF));
}

// ---- head: logits_mlp, loss, reg, register-resident rehearsal scan ----
__global__ __launch_bounds__(256) void k5_head(const float* __restrict__ bag,
    const float* __restrict__ cm, const float* __restrict__ cmn,
    const float* __restrict__ distsIn, const int* __restrict__ y,
    const float* __restrict__ Wc, const float* __restrict__ bc,
    float* __restrict__ out) {
  __shared__ float simL[32][2], logitL[32][2], bagn[32];
  __shared__ int ownS[512];
  __shared__ float dot01S;
  int tid = threadIdx.x;
  int lane = tid & 63, wv = tid >> 6;
  // phase 1: per-bag raw dots with cls_means, Wc, and norms
  for (int j = 0; j < 8; j++) {
    int b = wv * 8 + j;
    const float* br = bag + b * 512;
    float s0 = 0, s1 = 0, w0 = 0, w1 = 0, n2 = 0;
    for (int l = lane; l < 500; l += 64) {
      float v = br[l];
      s0 += v * cm[l]; s1 += v * cm[512 + l];
      w0 += v * Wc[l * 2]; w1 += v * Wc[l * 2 + 1];
      n2 += v * v;
    }
#pragma unroll
    for (int m = 32; m > 0; m >>= 1) {
      s0 += __shfl_xor(s0, m); s1 += __shfl_xor(s1, m);
      w0 += __shfl_xor(w0, m); w1 += __shfl_xor(w1, m);
      n2 += __shfl_xor(n2, m);
    }
    if (lane == 0) {
      simL[b][0] = s0; simL[b][1] = s1;
      logitL[b][0] = w0 + bc[0]; logitL[b][1] = w1 + bc[1];
      bagn[b] = sqrtf(n2);
    }
  }
  if (wv == 1) {
    float d = 0.f;
    for (int l = lane; l < 500; l += 64) d += cm[l] * cm[512 + l];
#pragma unroll
    for (int m = 32; m > 0; m >>= 1) d += __shfl_xor(d, m);
    if (lane == 0) dot01S = d;
  }
  __syncthreads();
  if (tid < 64) out[tid] = logitL[tid >> 1][tid & 1];
  if (tid == 64) {  // wave 1: loss + reg (overlaps wave-0 scan)
    float acc = 0.f;
    for (int b = 0; b < 32; b++) {
      int yb = y[b];
      float p = simL[b][yb] * 2.0f;        // /TEMP, TEMP=0.5
      float ng = simL[b][1 - yb] * 2.0f;
      float mx = fmaxf(p, ng);
      float lse = mx + logf(expf(p - mx) + expf(ng - mx));
      acc += p - lse;
    }
    out[64] = -acc / 32.f;
    out[65] = 1.f + dot01S / (fmaxf(cmn[0], EPSF) * fmaxf(cmn[1], EPSF));
  }
  // wave 0: 32-step scan, dists in registers (8 slots/lane), shfl argmin
  if (wv == 0) {
    float dreg[8]; int oreg[8];
#pragma unroll
    for (int j = 0; j < 8; j++) { dreg[j] = distsIn[j * 64 + lane]; oreg[j] = -1; }
    for (int i = 0; i < 32; i++) {
      int ci = y[i];
      int jb = ci * 4;
      float v = dreg[jb]; int p = lane;
#pragma unroll
      for (int jj = 1; jj < 4; jj++) {
        float nv = dreg[jb + jj]; int np = jj * 64 + lane;
        if (nv < v || (nv == v && np < p)) { v = nv; p = np; }
      }
#pragma unroll
      for (int s = 1; s < 64; s <<= 1) {
        float ov = __shfl_xor(v, s); int op = __shfl_xor(p, s);
        if (ov < v || (ov == v && op < p)) { v = ov; p = op; }
      }
      float d = simL[i][ci] / (fmaxf(cmn[ci], EPSF) * fmaxf(bagn[i], EPSF));
      if (d > v && (p & 63) == lane) {
        int jj = jb + (p >> 6);
        dreg[jj] = d; oreg[jj] = i;
      }
    }
#pragma unroll
    for (int j = 0; j < 8; j++) ownS[j * 64 + lane] = oreg[j];
  }
  __syncthreads();
  // write replaced rows (owner holds last writer per slot)
  for (int s = 0; s < 512; s++) {
    int o = ownS[s];
    if (o >= 0)
      for (int l = tid; l < 500; l += 256) out[66 + s * 500 + l] = bag[o * 512 + l];
  }
}

extern "C" void kernel_launch(void* const* d_in, const int* in_sizes, int n_in,
                              void* d_out, int out_size, void* d_ws, size_t ws_size,
                              hipStream_t stream) {
  const float* x  = (const float*)d_in[0];
  const int*   y  = (const int*)d_in[1];
  const float* W1 = (const float*)d_in[2];
  const float* b1 = (const float*)d_in[3];
  const float* Wa = (const float*)d_in[4];
  const float* ba = (const float*)d_in[5];
  const float* Va = (const float*)d_in[6];
  const float* bv = (const float*)d_in[7];
  const float* Wc = (const float*)d_in[8];
  const float* bc = (const float*)d_in[9];
  const float* reh = (const float*)d_in[10];
  float* out = (float*)d_out;

  char* ws = (char*)d_ws;
  unsigned short* H   = (unsigned short*)ws;
  float*          a   = (float*)(ws + 134217728);
  unsigned short* W1T = (unsigned short*)(ws + 134742016);
  unsigned short* WaT = (unsigned short*)(ws + 135790592);
  float*          bag = (float*)(ws + 135921664);
  float*          cm  = (float*)(ws + 135987200);
  float*          cmn = (float*)(ws + 135991296);
  float*          dst = (float*)(ws + 135991552);

  hipMemsetAsync(bag, 0, 65536, stream);
  k0_w1t<<<2048, 256, 0, stream>>>(W1, W1T);
  k0_wat<<<256, 256, 0, stream>>>(Wa, WaT);
  k1_gemm1<<<4096, 256, 0, stream>>>(x, W1T, b1, H);
  k2_attn<<<1024, 256, 0, stream>>>(H, WaT, ba, Va, bv, a);
  k3_softmax<<<32, 256, 0, stream>>>(a);
  k4_bag<<<512, 256, 0, stream>>>(H, a, bag);
  k5_copy<<<1001, 256, 0, stream>>>(reh, out);
  k5_means<<<2, 256, 0, stream>>>(reh, cm);
  k5_cmnorm<<<2, 256, 0, stream>>>(cm, cmn);
  k5_dists<<<512, 64, 0, stream>>>(reh, cm, cmn, dst);
  k5_head<<<1, 256, 0, stream>>>(bag, cm, cmn, dst, y, Wc, bc, out);
}

// Round 4
// 1038.274 us; speedup vs baseline: 1.1202x; 1.0403x over previous
//
#include <hip/hip_runtime.h>

// BClassifier fused pipeline for MI355X (gfx950). Round 3 (resubmit after
// infra failure — source identical to round 3):
//  - GEMM1 restructured: block tile 128x512 (full N), 512 threads / 8 waves,
//    A converted fp32->bf16 during staging (halves LDS traffic), x read
//    exactly once from HBM. XOR-swizzled LDS chunks throughout.
//  - Everything else carried from round 2.

#define EPSF 1e-8f

typedef float v4f __attribute__((ext_vector_type(4)));
typedef short v8s __attribute__((ext_vector_type(8)));

__device__ __forceinline__ unsigned short f2bf(float f) {
  unsigned u = __float_as_uint(f);
  u = (u + 0x7fffu + ((u >> 16) & 1u)) >> 16;  // RNE
  return (unsigned short)u;
}
__device__ __forceinline__ float bf2f(unsigned short b) {
  return __uint_as_float(((unsigned)b) << 16);
}
// pack two floats' high halves: low short = trunc(a), high short = trunc(b)
__device__ __forceinline__ unsigned pk(float a, float b) {
  return __builtin_amdgcn_perm(__float_as_uint(b), __float_as_uint(a), 0x07060302u);
}
__device__ __forceinline__ void gll16(const void* g, void* l) {
  __builtin_amdgcn_global_load_lds((const __attribute__((address_space(1))) void*)g,
                                   (__attribute__((address_space(3))) void*)l, 16, 0, 0);
}

// ---- prep: W1 [1024][500] f32 -> W1T [512][1024] bf16 (zero-padded cols) ----
__global__ void k0_w1t(const float* __restrict__ W1, unsigned short* __restrict__ W1T) {
  int idx = blockIdx.x * 256 + threadIdx.x;  // 512*1024
  int n = idx >> 10, k = idx & 1023;
  float v = (n < 500) ? W1[k * 500 + n] : 0.f;
  W1T[idx] = f2bf(v);
}
// ---- prep: Wa [500][128] f32 -> WaT [128][512] bf16 (zero-padded rows) ----
__global__ void k0_wat(const float* __restrict__ Wa, unsigned short* __restrict__ WaT) {
  int idx = blockIdx.x * 256 + threadIdx.x;  // 128*512
  int d = idx >> 9, l = idx & 511;
  float v = (l < 500) ? Wa[l * 128 + d] : 0.f;
  WaT[idx] = f2bf(v);
}

// ---- GEMM1: H = relu(x @ W1 + b1), bf16 out [131072][512] ----
// block tile 128x512, BK=64, 512 threads (8 waves, each 64x128)
__global__ __launch_bounds__(512, 2) void k1_gemm1(const float* __restrict__ x,
    const unsigned short* __restrict__ W1T, const float* __restrict__ b1,
    unsigned short* __restrict__ H) {
  __shared__ unsigned short As[128 * 64];   // 16 KB bf16, 16B-chunk xor-swizzled
  __shared__ unsigned short Bs[512 * 64];   // 64 KB bf16 [n][k], swizzled
  int tid = threadIdx.x;
  int lane = tid & 63, wv = tid >> 6;
  int wm = (wv & 1) * 64, wn = (wv >> 1) * 128;
  int l15 = lane & 15, quad = lane >> 4;
  size_t m0 = (size_t)blockIdx.x * 128;
  v4f acc[4][8];
#pragma unroll
  for (int i = 0; i < 4; i++)
#pragma unroll
    for (int j = 0; j < 8; j++) acc[i][j] = (v4f)(0.f);

  for (int kt = 0; kt < 1024; kt += 64) {
    const float* gA = x + m0 * 1024 + kt;
    const unsigned short* gB = W1T + kt;
    // A: 128 rows x 16 fp32-chunks of 16B -> convert -> bf16 LDS (swizzled)
#pragma unroll
    for (int p = 0; p < 4; p++) {
      int ci = p * 512 + tid;
      int r = ci >> 4, c4 = ci & 15;
      v4f v = *(const v4f*)(gA + (size_t)r * 1024 + c4 * 4);
      unsigned u0 = pk(v.x, v.y), u1 = pk(v.z, v.w);
      int c8 = c4 >> 1, half = c4 & 1;
      unsigned* dst = (unsigned*)(As + r * 64 + (((c8 ^ (r & 7)) << 3) | (half << 2)));
      dst[0] = u0; dst[1] = u1;
    }
    // B: 512 rows x 8 chunks of 16B, async direct-to-LDS (swizzled source)
#pragma unroll
    for (int p = 0; p < 8; p++) {
      int ci = p * 512 + tid;
      int r = ci >> 3, c = (ci & 7) ^ (r & 7);
      gll16(gB + (size_t)r * 1024 + c * 8, Bs + ci * 8);
    }
    __syncthreads();
#pragma unroll
    for (int kk = 0; kk < 64; kk += 32) {
      v8s af[4], bf[8];
      int cb = (kk >> 3) + quad;  // k-chunk 0..7
#pragma unroll
      for (int mi = 0; mi < 4; mi++) {
        int r = wm + mi * 16 + l15;
        af[mi] = *(const v8s*)(As + r * 64 + ((cb ^ (r & 7)) << 3));
      }
#pragma unroll
      for (int ni = 0; ni < 8; ni++) {
        int r = wn + ni * 16 + l15;
        bf[ni] = *(const v8s*)(Bs + r * 64 + ((cb ^ (r & 7)) << 3));
      }
#pragma unroll
      for (int mi = 0; mi < 4; mi++)
#pragma unroll
        for (int ni = 0; ni < 8; ni++)
          acc[mi][ni] = __builtin_amdgcn_mfma_f32_16x16x32_bf16(af[mi], bf[ni], acc[mi][ni], 0, 0, 0);
    }
    __syncthreads();
  }
#pragma unroll
  for (int mi = 0; mi < 4; mi++) {
#pragma unroll
    for (int ni = 0; ni < 8; ni++) {
      int col = wn + ni * 16 + l15;
      float bias = (col < 500) ? b1[col] : 0.f;
#pragma unroll
      for (int r = 0; r < 4; r++) {
        size_t row = m0 + wm + mi * 16 + quad * 4 + r;
        float v = (col < 500) ? fmaxf(acc[mi][ni][r] + bias, 0.f) : 0.f;
        H[row * 512 + col] = f2bf(v);
      }
    }
  }
}

// ---- GEMM2: a = relu(H @ Wa + ba) @ Va + bv  -> [131072] f32 ----
__global__ __launch_bounds__(256) void k2_attn(const unsigned short* __restrict__ H,
    const unsigned short* __restrict__ WaT, const float* __restrict__ ba,
    const float* __restrict__ Va, const float* __restrict__ bv,
    float* __restrict__ aout) {
  __shared__ unsigned short Hs[128 * 64];
  __shared__ unsigned short Ws[128 * 64];
  size_t m0 = (size_t)blockIdx.x * 128;
  int tid = threadIdx.x;
  int lane = tid & 63, wv = tid >> 6;
  int wm = wv * 32;  // each wave owns 32 rows, all 128 cols
  int l15 = lane & 15, quad = lane >> 4, m7 = l15 & 7;
  v4f acc[2][8];
  for (int i = 0; i < 2; i++)
    for (int jj = 0; jj < 8; jj++) acc[i][jj] = (v4f)(0.f);

  for (int kt = 0; kt < 512; kt += 64) {
    const unsigned short* gH = H + m0 * 512 + kt;
    const unsigned short* gW = WaT + kt;
#pragma unroll
    for (int p = 0; p < 4; p++) {
      int ci = p * 256 + tid;
      int r = ci >> 3, pc = ci & 7;
      int c = pc ^ (r & 7);
      gll16(gH + (size_t)r * 512 + c * 8, Hs + ci * 8);
    }
#pragma unroll
    for (int p = 0; p < 4; p++) {
      int ci = p * 256 + tid;
      int r = ci >> 3, pc = ci & 7;
      int c = pc ^ (r & 7);
      gll16(gW + (size_t)r * 512 + c * 8, Ws + ci * 8);
    }
    __syncthreads();
#pragma unroll
    for (int kk = 0; kk < 64; kk += 32) {
      v8s af[2], bf[8];
      int cb = (kk >> 3) + quad;
#pragma unroll
      for (int mi = 0; mi < 2; mi++)
        af[mi] = *(const v8s*)(Hs + (wm + mi * 16 + l15) * 64 + ((cb ^ m7) << 3));
#pragma unroll
      for (int ni = 0; ni < 8; ni++)
        bf[ni] = *(const v8s*)(Ws + (ni * 16 + l15) * 64 + ((cb ^ m7) << 3));
#pragma unroll
      for (int mi = 0; mi < 2; mi++)
#pragma unroll
        for (int ni = 0; ni < 8; ni++)
          acc[mi][ni] = __builtin_amdgcn_mfma_f32_16x16x32_bf16(af[mi], bf[ni], acc[mi][ni], 0, 0, 0);
    }
    __syncthreads();
  }
  float bav[8], vav[8];
#pragma unroll
  for (int ni = 0; ni < 8; ni++) {
    int n = ni * 16 + l15;
    bav[ni] = ba[n];
    vav[ni] = Va[n];
  }
  float bv0 = bv[0];
#pragma unroll
  for (int mi = 0; mi < 2; mi++) {
#pragma unroll
    for (int r = 0; r < 4; r++) {
      float s = 0.f;
#pragma unroll
      for (int ni = 0; ni < 8; ni++) s += fmaxf(acc[mi][ni][r] + bav[ni], 0.f) * vav[ni];
      s += __shfl_xor(s, 1); s += __shfl_xor(s, 2);
      s += __shfl_xor(s, 4); s += __shfl_xor(s, 8);
      if (l15 == 0) aout[m0 + wm + mi * 16 + quad * 4 + r] = s + bv0;
    }
  }
}

// ---- softmax over N=4096 per bag, in place ----
__global__ void k3_softmax(float* __restrict__ a) {
  __shared__ float red[256];
  int b = blockIdx.x, tid = threadIdx.x;
  float* row = a + b * 4096;
  float m = -1e30f;
  for (int i = tid; i < 4096; i += 256) m = fmaxf(m, row[i]);
  red[tid] = m; __syncthreads();
  for (int s = 128; s > 0; s >>= 1) { if (tid < s) red[tid] = fmaxf(red[tid], red[tid + s]); __syncthreads(); }
  m = red[0]; __syncthreads();
  float sum = 0.f;
  for (int i = tid; i < 4096; i += 256) { float e = expf(row[i] - m); row[i] = e; sum += e; }
  red[tid] = sum; __syncthreads();
  for (int s = 128; s > 0; s >>= 1) { if (tid < s) red[tid] += red[tid + s]; __syncthreads(); }
  float inv = 1.f / red[0];
  for (int i = tid; i < 4096; i += 256) row[i] *= inv;
}

// ---- bag_feat[b][l] = sum_n A[b][n] * H[b,n,l], atomic accumulate ----
__global__ void k4_bag(const unsigned short* __restrict__ H, const float* __restrict__ A,
                       float* __restrict__ bag) {
  int bid = blockIdx.x;          // 32 bags x 16 chunks
  int b = bid >> 4, ch = bid & 15;
  int tid = threadIdx.x;
  size_t base = ((size_t)b * 4096 + ch * 256) * 512;
  const float* Ab = A + b * 4096 + ch * 256;
  float s0 = 0.f, s1 = 0.f;
  for (int n = 0; n < 256; n += 4) {
#pragma unroll
    for (int jj = 0; jj < 4; jj++) {
      float w = Ab[n + jj];
      unsigned hv = *(const unsigned*)(H + base + (size_t)(n + jj) * 512 + tid * 2);
      s0 += w * bf2f((unsigned short)(hv & 0xffffu));
      s1 += w * bf2f((unsigned short)(hv >> 16));
    }
  }
  atomicAdd(&bag[b * 512 + tid * 2], s0);
  atomicAdd(&bag[b * 512 + tid * 2 + 1], s1);
}

// ---- copy rehearsal -> out[66..] ----
__global__ void k5_copy(const float* __restrict__ reh, float* __restrict__ out) {
  int idx = blockIdx.x * 256 + threadIdx.x;
  if (idx < 256000) out[66 + idx] = reh[idx];
}

// ---- cls_means [2][512] (pad 0), coalesced row accumulation ----
__global__ void k5_means(const float* __restrict__ reh, float* __restrict__ cm) {
  int c = blockIdx.x, tid = threadIdx.x;  // grid 2 x 256
  const float* base = reh + c * 128000;
  float s0 = 0.f, s1 = 0.f;
  for (int q = 0; q < 256; q++) {
    const float* row = base + q * 500;
    s0 += row[tid];
    if (tid + 256 < 500) s1 += row[tid + 256];
  }
  cm[c * 512 + tid] = s0 * (1.f / 256.f);
  int l2 = tid + 256;
  cm[c * 512 + l2] = (l2 < 500) ? s1 * (1.f / 256.f) : 0.f;
}

__global__ void k5_cmnorm(const float* __restrict__ cm, float* __restrict__ cmn) {
  __shared__ float red[256];
  int c = blockIdx.x, tid = threadIdx.x;
  float v = 0.f;
  for (int l = tid; l < 512; l += 256) { float xx = cm[c * 512 + l]; v += xx * xx; }
  red[tid] = v; __syncthreads();
  for (int s = 128; s > 0; s >>= 1) { if (tid < s) red[tid] += red[tid + s]; __syncthreads(); }
  if (tid == 0) cmn[c] = sqrtf(red[0]);
}

// ---- cls_dists[c][p] = cos(cls_means[c], reh[c][p]) ----
__global__ void k5_dists(const float* __restrict__ reh, const float* __restrict__ cm,
                         const float* __restrict__ cmn, float* __restrict__ dists) {
  int bid = blockIdx.x;  // 512
  int c = bid >> 8, p = bid & 255;
  int lane = threadIdx.x;  // 64
  const float* row = reh + (c * 256 + p) * 500;
  const float* cmr = cm + c * 512;
  float dot = 0.f, n2 = 0.f;
  for (int l = lane; l < 500; l += 64) { float r = row[l]; dot += r * cmr[l]; n2 += r * r; }
#pragma unroll
  for (int m = 32; m > 0; m >>= 1) { dot += __shfl_xor(dot, m); n2 += __shfl_xor(n2, m); }
  if (lane == 0)
    dists[c * 256 + p] = dot / (fmaxf(cmn[c], EPSF) * fmaxf(sqrtf(n2), EPSF));
}

// ---- head: logits_mlp, loss, reg, register-resident rehearsal scan ----
__global__ __launch_bounds__(256) void k5_head(const float* __restrict__ bag,
    const float* __restrict__ cm, const float* __restrict__ cmn,
    const float* __restrict__ distsIn, const int* __restrict__ y,
    const float* __restrict__ Wc, const float* __restrict__ bc,
    float* __restrict__ out) {
  __shared__ float simL[32][2], logitL[32][2], bagn[32];
  __shared__ int ownS[512];
  __shared__ float dot01S;
  int tid = threadIdx.x;
  int lane = tid & 63, wv = tid >> 6;
  // phase 1: per-bag raw dots with cls_means, Wc, and norms
  for (int j = 0; j < 8; j++) {
    int b = wv * 8 + j;
    const float* br = bag + b * 512;
    float s0 = 0, s1 = 0, w0 = 0, w1 = 0, n2 = 0;
    for (int l = lane; l < 500; l += 64) {
      float v = br[l];
      s0 += v * cm[l]; s1 += v * cm[512 + l];
      w0 += v * Wc[l * 2]; w1 += v * Wc[l * 2 + 1];
      n2 += v * v;
    }
#pragma unroll
    for (int m = 32; m > 0; m >>= 1) {
      s0 += __shfl_xor(s0, m); s1 += __shfl_xor(s1, m);
      w0 += __shfl_xor(w0, m); w1 += __shfl_xor(w1, m);
      n2 += __shfl_xor(n2, m);
    }
    if (lane == 0) {
      simL[b][0] = s0; simL[b][1] = s1;
      logitL[b][0] = w0 + bc[0]; logitL[b][1] = w1 + bc[1];
      bagn[b] = sqrtf(n2);
    }
  }
  if (wv == 1) {
    float d = 0.f;
    for (int l = lane; l < 500; l += 64) d += cm[l] * cm[512 + l];
#pragma unroll
    for (int m = 32; m > 0; m >>= 1) d += __shfl_xor(d, m);
    if (lane == 0) dot01S = d;
  }
  __syncthreads();
  if (tid < 64) out[tid] = logitL[tid >> 1][tid & 1];
  if (tid == 64) {  // wave 1: loss + reg (overlaps wave-0 scan)
    float acc = 0.f;
    for (int b = 0; b < 32; b++) {
      int yb = y[b];
      float p = simL[b][yb] * 2.0f;        // /TEMP, TEMP=0.5
      float ng = simL[b][1 - yb] * 2.0f;
      float mx = fmaxf(p, ng);
      float lse = mx + logf(expf(p - mx) + expf(ng - mx));
      acc += p - lse;
    }
    out[64] = -acc / 32.f;
    out[65] = 1.f + dot01S / (fmaxf(cmn[0], EPSF) * fmaxf(cmn[1], EPSF));
  }
  // wave 0: 32-step scan, dists in registers (8 slots/lane), shfl argmin
  if (wv == 0) {
    float dreg[8]; int oreg[8];
#pragma unroll
    for (int j = 0; j < 8; j++) { dreg[j] = distsIn[j * 64 + lane]; oreg[j] = -1; }
    for (int i = 0; i < 32; i++) {
      int ci = y[i];
      int jb = ci * 4;
      float v = dreg[jb]; int p = lane;
#pragma unroll
      for (int jj = 1; jj < 4; jj++) {
        float nv = dreg[jb + jj]; int np = jj * 64 + lane;
        if (nv < v || (nv == v && np < p)) { v = nv; p = np; }
      }
#pragma unroll
      for (int s = 1; s < 64; s <<= 1) {
        float ov = __shfl_xor(v, s); int op = __shfl_xor(p, s);
        if (ov < v || (ov == v && op < p)) { v = ov; p = op; }
      }
      float d = simL[i][ci] / (fmaxf(cmn[ci], EPSF) * fmaxf(bagn[i], EPSF));
      if (d > v && (p & 63) == lane) {
        int jj = jb + (p >> 6);
        dreg[jj] = d; oreg[jj] = i;
      }
    }
#pragma unroll
    for (int j = 0; j < 8; j++) ownS[j * 64 + lane] = oreg[j];
  }
  __syncthreads();
  // write replaced rows (owner holds last writer per slot)
  for (int s = 0; s < 512; s++) {
    int o = ownS[s];
    if (o >= 0)
      for (int l = tid; l < 500; l += 256) out[66 + s * 500 + l] = bag[o * 512 + l];
  }
}

extern "C" void kernel_launch(void* const* d_in, const int* in_sizes, int n_in,
                              void* d_out, int out_size, void* d_ws, size_t ws_size,
                              hipStream_t stream) {
  const float* x  = (const float*)d_in[0];
  const int*   y  = (const int*)d_in[1];
  const float* W1 = (const float*)d_in[2];
  const float* b1 = (const float*)d_in[3];
  const float* Wa = (const float*)d_in[4];
  const float* ba = (const float*)d_in[5];
  const float* Va = (const float*)d_in[6];
  const float* bv = (const float*)d_in[7];
  const float* Wc = (const float*)d_in[8];
  const float* bc = (const float*)d_in[9];
  const float* reh = (const float*)d_in[10];
  float* out = (float*)d_out;

  char* ws = (char*)d_ws;
  unsigned short* H   = (unsigned short*)ws;
  float*          a   = (float*)(ws + 134217728);
  unsigned short* W1T = (unsigned short*)(ws + 134742016);
  unsigned short* WaT = (unsigned short*)(ws + 135790592);
  float*          bag = (float*)(ws + 135921664);
  float*          cm  = (float*)(ws + 135987200);
  float*          cmn = (float*)(ws + 135991296);
  float*          dst = (float*)(ws + 135991552);

  hipMemsetAsync(bag, 0, 65536, stream);
  k0_w1t<<<2048, 256, 0, stream>>>(W1, W1T);
  k0_wat<<<256, 256, 0, stream>>>(Wa, WaT);
  k1_gemm1<<<1024, 512, 0, stream>>>(x, W1T, b1, H);
  k2_attn<<<1024, 256, 0, stream>>>(H, WaT, ba, Va, bv, a);
  k3_softmax<<<32, 256, 0, stream>>>(a);
  k4_bag<<<512, 256, 0, stream>>>(H, a, bag);
  k5_copy<<<1001, 256, 0, stream>>>(reh, out);
  k5_means<<<2, 256, 0, stream>>>(reh, cm);
  k5_cmnorm<<<2, 256, 0, stream>>>(cm, cmn);
  k5_dists<<<512, 64, 0, stream>>>(reh, cm, cmn, dst);
  k5_head<<<1, 256, 0, stream>>>(bag, cm, cmn, dst, y, Wc, bc, out);
}